// Round 10
// baseline (54.034 us; speedup 1.0000x reference)
//
#include <hip/hip_runtime.h>

// Problem constants: N=8, C=1024, D=128, K=64, R=256
#define N_ 8
#define C_ 1024
#define D_ 128
#define K_ 64
#define R_ 256
#define ROWS 8   // c-rows per block

typedef float fvec4 __attribute__((ext_vector_type(4)));

// out[n,c,k,d] = (xhat[n,c,d] - cent[n,k,d]) / (8 * ||xhat[n,c]-cent[n,k]||)
// (softmax cancels under the per-k l2norm; final l2norm over K*D == sqrt(K)=8)
//
// R9: ROWS 4 -> 8 (1024 blocks, 4/CU). cent registers reused 8x, 8x fewer
// block heads than R1, 64KB contiguous store run per block. Same per-row
// pipeline as the 51.8us R8: half-wave butterfly, diff[8]/id[8], then an
// 8-store coalesced burst (wave writes 1KB/instruction).
__global__ __launch_bounds__(256) void vlad_deep_kernel(
    const float* __restrict__ x,            // (N, C, D)
    const float* __restrict__ cluster,      // (N, R, D)
    const int*   __restrict__ cluster_idx,  // (K,)
    float*       __restrict__ out)          // (N, C, K*D)
{
    const int bid = blockIdx.x;
    const int n   = bid & 7;
    const int c0  = (bid >> 3) * ROWS;
    const int t   = threadIdx.x;
    const int l   = t & 31;          // lane within half-wave
    const int h   = t >> 5;          // half-wave id 0..7

    // ---- cent rows for this thread's 8 k's: loaded once, live in registers ----
    const float* cbase = cluster + (size_t)n * (R_ * D_);
    fvec4 cv[8];
    #pragma unroll
    for (int p = 0; p < 8; ++p)
        cv[p] = *(const fvec4*)(cbase + (size_t)cluster_idx[p * 8 + h] * D_ + l * 4);

    const float* xrow0 = x + (size_t)(n * C_ + c0) * D_ + l * 4;
    fvec4 xv = *(const fvec4*)xrow0;                     // row 0

    float* ob = out + (size_t)(n * C_ + c0) * (K_ * D_) + (size_t)t * 4;

    #pragma unroll
    for (int rr = 0; rr < ROWS; ++rr) {
        // prefetch next row's x before this row's compute
        fvec4 xnext;
        if (rr + 1 < ROWS)
            xnext = *(const fvec4*)(xrow0 + (size_t)(rr + 1) * D_);

        // normalize
        float nx = fmaf(xv.x, xv.x, fmaf(xv.y, xv.y, fmaf(xv.z, xv.z, xv.w * xv.w)));
        #pragma unroll
        for (int m = 1; m <= 16; m <<= 1) nx += __shfl_xor(nx, m, 32);
        const float rinv = 1.0f / fmaxf(sqrtf(nx), 1e-12f);
        xv *= rinv;

        // distances -> diff/id in registers
        fvec4 diff[8];
        float id[8];
        #pragma unroll
        for (int p = 0; p < 8; ++p) {
            fvec4 d = xv - cv[p];
            diff[p] = d;
            float ds = fmaf(d.x, d.x, fmaf(d.y, d.y, fmaf(d.z, d.z, d.w * d.w)));
            #pragma unroll
            for (int m = 1; m <= 16; m <<= 1) ds += __shfl_xor(ds, m, 32);
            id[p] = 0.125f / fmaxf(sqrtf(ds), 1e-12f);   // includes 1/sqrt(K)
        }

        // coalesced store burst (wave writes 1KB contiguous per instruction)
        float* orow = ob + (size_t)rr * (K_ * D_);
        #pragma unroll
        for (int p = 0; p < 8; ++p)
            *(fvec4*)(orow + (size_t)p * 1024) = diff[p] * id[p];

        xv = xnext;
    }
}

extern "C" void kernel_launch(void* const* d_in, const int* in_sizes, int n_in,
                              void* d_out, int out_size, void* d_ws, size_t ws_size,
                              hipStream_t stream) {
    const float* x           = (const float*)d_in[0];
    const float* cluster     = (const float*)d_in[1];
    // d_in[2] = conv_w, d_in[3] = conv_b: mathematically cancelled, unused.
    const int*   cluster_idx = (const int*)d_in[4];
    float* out = (float*)d_out;

    dim3 grid(N_ * C_ / ROWS), block(256);   // 1024 blocks
    vlad_deep_kernel<<<grid, block, 0, stream>>>(x, cluster, cluster_idx, out);
}

// Round 11
// 52.013 us; speedup vs baseline: 1.0389x; 1.0389x over previous
//
#include <hip/hip_runtime.h>

// Problem constants: N=8, C=1024, D=128, K=64, R=256
#define N_ 8
#define C_ 1024
#define D_ 128
#define K_ 64
#define R_ 256
#define ROWS 4   // c-rows per block — R8 optimum (ROWS=8 regressed 51.8->54.0)

typedef float fvec4 __attribute__((ext_vector_type(4)));

// out[n,c,k,d] = (xhat[n,c,d] - cent[n,k,d]) / (8 * ||xhat[n,c]-cent[n,k]||)
// (softmax cancels under the per-k l2norm; final l2norm over K*D == sqrt(K)=8)
//
// Final structure (R8, 51.8us): 2048 blocks x 4 rows. cent float4s loaded
// once per block into registers (reused 4x); per row: half-wave butterfly
// norm, diff[8]/id[8] in registers, then an 8-store coalesced burst (wave
// writes 1KB contiguous per instruction). Kernel body ~42-44us at ~6.2 TB/s
// effective write BW (~90% of this box's fill rate); remainder of dur_us is
// fixed dispatch overhead (~8-10us, measured via the R6 two-dispatch split).
__global__ __launch_bounds__(256) void vlad_deep_kernel(
    const float* __restrict__ x,            // (N, C, D)
    const float* __restrict__ cluster,      // (N, R, D)
    const int*   __restrict__ cluster_idx,  // (K,)
    float*       __restrict__ out)          // (N, C, K*D)
{
    const int bid = blockIdx.x;
    const int n   = bid & 7;
    const int c0  = (bid >> 3) * ROWS;
    const int t   = threadIdx.x;
    const int l   = t & 31;          // lane within half-wave
    const int h   = t >> 5;          // half-wave id 0..7

    // ---- cent rows for this thread's 8 k's: loaded once, live in registers ----
    const float* cbase = cluster + (size_t)n * (R_ * D_);
    fvec4 cv[8];
    #pragma unroll
    for (int p = 0; p < 8; ++p)
        cv[p] = *(const fvec4*)(cbase + (size_t)cluster_idx[p * 8 + h] * D_ + l * 4);

    const float* xrow0 = x + (size_t)(n * C_ + c0) * D_ + l * 4;
    fvec4 xv = *(const fvec4*)xrow0;                     // row 0

    float* ob = out + (size_t)(n * C_ + c0) * (K_ * D_) + (size_t)t * 4;

    #pragma unroll
    for (int rr = 0; rr < ROWS; ++rr) {
        // prefetch next row's x before this row's compute
        fvec4 xnext;
        if (rr + 1 < ROWS)
            xnext = *(const fvec4*)(xrow0 + (size_t)(rr + 1) * D_);

        // normalize
        float nx = fmaf(xv.x, xv.x, fmaf(xv.y, xv.y, fmaf(xv.z, xv.z, xv.w * xv.w)));
        #pragma unroll
        for (int m = 1; m <= 16; m <<= 1) nx += __shfl_xor(nx, m, 32);
        const float rinv = 1.0f / fmaxf(sqrtf(nx), 1e-12f);
        xv *= rinv;

        // distances -> diff/id in registers
        fvec4 diff[8];
        float id[8];
        #pragma unroll
        for (int p = 0; p < 8; ++p) {
            fvec4 d = xv - cv[p];
            diff[p] = d;
            float ds = fmaf(d.x, d.x, fmaf(d.y, d.y, fmaf(d.z, d.z, d.w * d.w)));
            #pragma unroll
            for (int m = 1; m <= 16; m <<= 1) ds += __shfl_xor(ds, m, 32);
            id[p] = 0.125f / fmaxf(sqrtf(ds), 1e-12f);   // includes 1/sqrt(K)
        }

        // coalesced store burst (wave writes 1KB contiguous per instruction)
        float* orow = ob + (size_t)rr * (K_ * D_);
        #pragma unroll
        for (int p = 0; p < 8; ++p)
            *(fvec4*)(orow + (size_t)p * 1024) = diff[p] * id[p];

        xv = xnext;
    }
}

extern "C" void kernel_launch(void* const* d_in, const int* in_sizes, int n_in,
                              void* d_out, int out_size, void* d_ws, size_t ws_size,
                              hipStream_t stream) {
    const float* x           = (const float*)d_in[0];
    const float* cluster     = (const float*)d_in[1];
    // d_in[2] = conv_w, d_in[3] = conv_b: mathematically cancelled, unused.
    const int*   cluster_idx = (const int*)d_in[4];
    float* out = (float*)d_out;

    dim3 grid(N_ * C_ / ROWS), block(256);   // 2048 blocks
    vlad_deep_kernel<<<grid, block, 0, stream>>>(x, cluster, cluster_idx, out);
}